// Round 8
// baseline (422.029 us; speedup 1.0000x reference)
//
#include <hip/hip_runtime.h>
#include <math.h>

// ---------------------------------------------------------------------------
// GCN: h1 = relu(norm_agg(x@W1)+b1); h2 = norm_agg(h1@W2)+b2;
//      g = mean_pool(h2, batch); out = relu(g@W3+b3)@W4 + b4
// norm_agg(h)[d] = (sum_{e: dst=d} h[src]*dinv[src] + h[d]*dinv[d]) * dinv[d]
// Build: count -> scan -> two-level line-dense scatter -> per-block src sort.
// Aggregation: task = 32 consecutive dsts; TWO waves per task (half the edge
// segment each, private LDS acc, merged in epilogue) for 2x occupancy, with
// software-pipelined index prefetch. Collective src-sorted sweep keeps the
// read front L2-resident. GEMM epilogue pre-scales rows by dinv.
// Graph node-counts via binary search on sorted batch (no atomics).
// ---------------------------------------------------------------------------

__global__ __launch_bounds__(256) void k_zero(int* cnt, float* gsum,
                                              int n, int gsz) {
  int i = blockIdx.x * 256 + threadIdx.x;
  if (i < n) cnt[i] = 0;
  if (i < gsz) gsum[i] = 0.f;
}

__global__ __launch_bounds__(256) void k_count(const int* __restrict__ dst,
                                               int* __restrict__ cnt, int e) {
  int i = blockIdx.x * 256 + threadIdx.x;
  if (i < e) atomicAdd(&cnt[dst[i]], 1);
}

// Exclusive scan, level A: each block scans a 1024-element chunk.
__global__ __launch_bounds__(256) void k_scanA(const int* __restrict__ cnt,
                                               int* __restrict__ startArr,
                                               int* __restrict__ bsum, int n) {
  __shared__ int sh[256];
  int t = threadIdx.x, b = blockIdx.x;
  int base = b * 1024 + t * 4;
  int v0 = 0, v1 = 0, v2 = 0, v3 = 0;
  if (base + 3 < n) {
    int4 v = *(const int4*)&cnt[base];
    v0 = v.x; v1 = v.y; v2 = v.z; v3 = v.w;
  } else {
    if (base + 0 < n) v0 = cnt[base + 0];
    if (base + 1 < n) v1 = cnt[base + 1];
    if (base + 2 < n) v2 = cnt[base + 2];
  }
  int local = v0 + v1 + v2 + v3;
  sh[t] = local;
  __syncthreads();
  for (int off = 1; off < 256; off <<= 1) {
    int x = (t >= off) ? sh[t - off] : 0;
    __syncthreads();
    sh[t] += x;
    __syncthreads();
  }
  int excl = sh[t] - local;
  if (t == 255) bsum[b] = sh[255];
  if (base + 0 < n) startArr[base + 0] = excl;
  if (base + 1 < n) startArr[base + 1] = excl + v0;
  if (base + 2 < n) startArr[base + 2] = excl + v0 + v1;
  if (base + 3 < n) startArr[base + 3] = excl + v0 + v1 + v2;
}

// Level B: single block scans the (<=256) chunk totals, in place, exclusive.
__global__ __launch_bounds__(256) void k_scanB(int* __restrict__ bsum, int nb) {
  __shared__ int sh[256];
  int t = threadIdx.x;
  int v = (t < nb) ? bsum[t] : 0;
  sh[t] = v;
  __syncthreads();
  for (int off = 1; off < 256; off <<= 1) {
    int x = (t >= off) ? sh[t - off] : 0;
    __syncthreads();
    sh[t] += x;
    __syncthreads();
  }
  if (t < nb) bsum[t] = sh[t] - v;
}

// Level C: finalize scan; dinv = 1/sqrt(deg+1); init block/bucket cursors.
__global__ __launch_bounds__(256) void k_scanC(int* __restrict__ startArr,
                                               const int* __restrict__ bsum,
                                               const int* __restrict__ cnt,
                                               float* __restrict__ dinv,
                                               int* __restrict__ blockCursor,
                                               int* __restrict__ bucketCursor,
                                               int n) {
  int i = blockIdx.x * 256 + threadIdx.x;
  if (i >= n) return;
  int s = startArr[i] + bsum[i >> 10];
  startArr[i] = s;
  dinv[i] = 1.0f / sqrtf((float)(cnt[i] + 1));
  if ((i & 31) == 0) blockCursor[i >> 5] = s;
  if ((i & 2047) == 0) bucketCursor[i >> 11] = s;
}

// Pass 1: bin edges into 49 coarse buckets (2048 nodes each) with range-dense
// writes. Entry = (dstLow6<<22) | (src<<5) | dstLocal.
__global__ __launch_bounds__(256) void k_p1(const int* __restrict__ src,
                                            const int* __restrict__ dst,
                                            int* __restrict__ bucketCursor,
                                            int* __restrict__ tmp, int e) {
  __shared__ int hist[64];
  __shared__ int gbase[64];
  int t = threadIdx.x;
  int base = blockIdx.x * 2048;
  if (t < 64) hist[t] = 0;
  __syncthreads();
  int ent[8], rk[8], bk[8];
#pragma unroll
  for (int k = 0; k < 8; ++k) {
    int i = base + k * 256 + t;
    bool v = i < e;
    int s = v ? src[i] : 0;
    int d = v ? dst[i] : 0;
    bk[k] = d >> 11;
    ent[k] = (((d >> 5) & 63) << 22) | (s << 5) | (d & 31);
    rk[k] = v ? atomicAdd(&hist[bk[k]], 1) : -1;
  }
  __syncthreads();
  if (t < 64 && hist[t] > 0) gbase[t] = atomicAdd(&bucketCursor[t], hist[t]);
  __syncthreads();
#pragma unroll
  for (int k = 0; k < 8; ++k)
    if (rk[k] >= 0) tmp[gbase[bk[k]] + rk[k]] = ent[k];
}

// Pass 2: within each bucket (8 slices/bucket), bin entries to their dst-block
// segment (64 bins), range-dense writes; strip top 6 bits for final csr.
__global__ __launch_bounds__(256) void k_p2(const int* __restrict__ startArr,
                                            const int* __restrict__ tmp,
                                            int* __restrict__ blockCursor,
                                            int* __restrict__ csr, int n, int e) {
  __shared__ int hist[64];
  __shared__ int gbase[64];
  int b = blockIdx.x >> 3;
  int sl = blockIdx.x & 7;
  int lo_b = startArr[b << 11];
  int hi_b = (((b + 1) << 11) < n) ? startArr[(b + 1) << 11] : e;
  int len = hi_b - lo_b;
  int lo = lo_b + (int)(((long long)len * sl) >> 3);
  int hi = lo_b + (int)(((long long)len * (sl + 1)) >> 3);
  int t = threadIdx.x;
  for (int rbase = lo; rbase < hi; rbase += 2048) {
    if (t < 64) hist[t] = 0;
    __syncthreads();
    int ent[8], rk[8], bin[8];
#pragma unroll
    for (int k = 0; k < 8; ++k) {
      int i = rbase + k * 256 + t;
      bool v = i < hi;
      int en = v ? tmp[i] : 0;
      ent[k] = en;
      bin[k] = en >> 22;
      rk[k] = v ? atomicAdd(&hist[bin[k]], 1) : -1;
    }
    __syncthreads();
    if (t < 64 && hist[t] > 0)
      gbase[t] = atomicAdd(&blockCursor[(b << 6) + t], hist[t]);
    __syncthreads();
#pragma unroll
    for (int k = 0; k < 8; ++k)
      if (rk[k] >= 0) csr[gbase[bin[k]] + rk[k]] = ent[k] & 0x3FFFFF;
    __syncthreads();
  }
}

// Per-node-block (32 dsts) counting sort of the packed edge segment by
// src>>11 (64 bins of 2048 rows). Locality-only transform.
__global__ __launch_bounds__(256) void k_bsort(const int* __restrict__ startArr,
                                               int* __restrict__ csr, int n, int e) {
  __shared__ int in_sh[1024];
  __shared__ int out_sh[1024];
  __shared__ int hist[64];
  __shared__ int hscan[64];
  int nodeBase = blockIdx.x << 5;
  if (nodeBase >= n) return;
  int p0 = startArr[nodeBase];
  int p1 = (nodeBase + 32 < n) ? startArr[nodeBase + 32] : e;
  int seg = p1 - p0;
  if (seg <= 0 || seg > 1024) return;  // block-uniform exit
  int t = threadIdx.x;
  if (t < 64) hist[t] = 0;
  __syncthreads();
  for (int i = t; i < seg; i += 256) {
    int v = csr[p0 + i];
    in_sh[i] = v;
    atomicAdd(&hist[v >> 16], 1);  // (src<<5)>>16 == src>>11
  }
  __syncthreads();
  if (t == 0) {
    int s = 0;
    for (int b = 0; b < 64; ++b) {
      hscan[b] = s;
      s += hist[b];
    }
  }
  __syncthreads();
  for (int i = t; i < seg; i += 256) {
    int v = in_sh[i];
    int pos = atomicAdd(&hscan[v >> 16], 1);
    out_sh[pos] = v;
  }
  __syncthreads();
  for (int i = t; i < seg; i += 256) csr[p0 + i] = out_sh[i];
}

// Y[N,64] = (X[N,64] @ W[64,64]) * dinv[row]  (row-scaled epilogue).
__global__ __launch_bounds__(256) void k_gemm64s(const float* __restrict__ X,
                                                 const float* __restrict__ W,
                                                 const float* __restrict__ dinv,
                                                 float* __restrict__ Y, int n) {
  __shared__ float Xs[64 * 65];
  __shared__ float Ws[64 * 64];
  int t = threadIdx.x;
  int r0 = blockIdx.x << 6;
  for (int i = t * 4; i < 4096; i += 1024)
    *(float4*)&Ws[i] = *(const float4*)&W[i];
  for (int s = t; s < 1024; s += 256) {
    int r = s >> 4, c4 = (s & 15) << 2;
    float4 v = make_float4(0.f, 0.f, 0.f, 0.f);
    if (r0 + r < n) v = *(const float4*)&X[(size_t)(r0 + r) * 64 + c4];
    Xs[r * 65 + c4 + 0] = v.x;
    Xs[r * 65 + c4 + 1] = v.y;
    Xs[r * 65 + c4 + 2] = v.z;
    Xs[r * 65 + c4 + 3] = v.w;
  }
  __syncthreads();
  int c4 = (t & 15) << 2;
  int rb = (t >> 4) << 2;
  float4 a0 = {0, 0, 0, 0}, a1 = {0, 0, 0, 0}, a2 = {0, 0, 0, 0}, a3 = {0, 0, 0, 0};
  for (int k = 0; k < 64; ++k) {
    float4 w = *(const float4*)&Ws[k * 64 + c4];
    float x0 = Xs[(rb + 0) * 65 + k];
    float x1 = Xs[(rb + 1) * 65 + k];
    float x2 = Xs[(rb + 2) * 65 + k];
    float x3 = Xs[(rb + 3) * 65 + k];
    a0.x += x0 * w.x; a0.y += x0 * w.y; a0.z += x0 * w.z; a0.w += x0 * w.w;
    a1.x += x1 * w.x; a1.y += x1 * w.y; a1.z += x1 * w.z; a1.w += x1 * w.w;
    a2.x += x2 * w.x; a2.y += x2 * w.y; a2.z += x2 * w.z; a2.w += x2 * w.w;
    a3.x += x3 * w.x; a3.y += x3 * w.y; a3.z += x3 * w.z; a3.w += x3 * w.w;
  }
  int r = r0 + rb;
  if (r + 0 < n) {
    float s0 = dinv[r + 0];
    a0.x *= s0; a0.y *= s0; a0.z *= s0; a0.w *= s0;
    *(float4*)&Y[(size_t)(r + 0) * 64 + c4] = a0;
  }
  if (r + 1 < n) {
    float s1 = dinv[r + 1];
    a1.x *= s1; a1.y *= s1; a1.z *= s1; a1.w *= s1;
    *(float4*)&Y[(size_t)(r + 1) * 64 + c4] = a1;
  }
  if (r + 2 < n) {
    float s2 = dinv[r + 2];
    a2.x *= s2; a2.y *= s2; a2.z *= s2; a2.w *= s2;
    *(float4*)&Y[(size_t)(r + 2) * 64 + c4] = a2;
  }
  if (r + 3 < n) {
    float s3 = dinv[r + 3];
    a3.x *= s3; a3.y *= s3; a3.z *= s3; a3.w *= s3;
    *(float4*)&Y[(size_t)(r + 3) * 64 + c4] = a3;
  }
}

// Aggregation v3: 2 tasks per block, 2 waves per task (each half of the edge
// segment into a private 8 KB LDS acc; merged after barrier). Rounds of 16
// edges with software-pipelined index prefetch.
// POOL=0: out = relu(v), POOL=1: atomicAdd into gsum.
template <int POOL>
__global__ __launch_bounds__(256) void k_agg3(
    const float* __restrict__ Hs, const int* __restrict__ csr,
    const int* __restrict__ startArr, const float* __restrict__ dinv,
    const float* __restrict__ bias, const int* __restrict__ batch,
    float* __restrict__ outv, float* __restrict__ gsum, int n, int e) {
  __shared__ float accs[4][32 * 64];  // 32 KB: private acc per wave
  int t = threadIdx.x;
  int w = t >> 6, lane = t & 63;
  int pair = w >> 1;   // task index within block
  int half = w & 1;    // which half of the edge segment
  int task = blockIdx.x * 2 + pair;
  int nodeBase = task << 5;
  bool valid = nodeBase < n;
  float* a = accs[w];
#pragma unroll 4
  for (int d = 0; d < 32; ++d) a[d * 64 + lane] = 0.f;
  if (valid) {
    int p0 = startArr[nodeBase];
    int p1 = (nodeBase + 32 < n) ? startArr[nodeBase + 32] : e;
    int c = p1 - p0;
    int ch = (c + 1) >> 1;
    int q0 = p0 + half * ch;
    int q1 = half ? p1 : (p0 + ch);
    int cc = q1 - q0;
    if (cc > 0) {
      int sub = lane & 15;
      int qlast = q1 - 1;
      int qq = q0 + sub;
      int pk = csr[qq < qlast ? qq : qlast];  // round-0 indices
      for (int rb = 0; rb < cc; rb += 16) {
        int pk_next = 0;
        bool more = (rb + 16) < cc;  // wave-uniform
        if (more) {
          int qn = q0 + rb + 16 + sub;
          pk_next = csr[qn < qlast ? qn : qlast];  // prefetch next round
        }
        int rem = cc - rb;  // wave-uniform
        int e0 = __builtin_amdgcn_readlane(pk, 0);
        int e1 = __builtin_amdgcn_readlane(pk, 1);
        int e2 = __builtin_amdgcn_readlane(pk, 2);
        int e3 = __builtin_amdgcn_readlane(pk, 3);
        int e4 = __builtin_amdgcn_readlane(pk, 4);
        int e5 = __builtin_amdgcn_readlane(pk, 5);
        int e6 = __builtin_amdgcn_readlane(pk, 6);
        int e7 = __builtin_amdgcn_readlane(pk, 7);
        int e8 = __builtin_amdgcn_readlane(pk, 8);
        int e9 = __builtin_amdgcn_readlane(pk, 9);
        int e10 = __builtin_amdgcn_readlane(pk, 10);
        int e11 = __builtin_amdgcn_readlane(pk, 11);
        int e12 = __builtin_amdgcn_readlane(pk, 12);
        int e13 = __builtin_amdgcn_readlane(pk, 13);
        int e14 = __builtin_amdgcn_readlane(pk, 14);
        int e15 = __builtin_amdgcn_readlane(pk, 15);
        float t0 = 0.f, t1 = 0.f, t2 = 0.f, t3 = 0.f;
        float t4 = 0.f, t5 = 0.f, t6 = 0.f, t7 = 0.f;
        float t8 = 0.f, t9 = 0.f, t10 = 0.f, t11 = 0.f;
        float t12 = 0.f, t13 = 0.f, t14 = 0.f, t15 = 0.f;
        {
          t0 = Hs[(size_t)(e0 >> 5) * 64 + lane];
          t1 = Hs[(size_t)(e1 >> 5) * 64 + lane];
          t2 = Hs[(size_t)(e2 >> 5) * 64 + lane];
          t3 = Hs[(size_t)(e3 >> 5) * 64 + lane];
        }
        if (rem > 4) {
          t4 = Hs[(size_t)(e4 >> 5) * 64 + lane];
          t5 = Hs[(size_t)(e5 >> 5) * 64 + lane];
          t6 = Hs[(size_t)(e6 >> 5) * 64 + lane];
          t7 = Hs[(size_t)(e7 >> 5) * 64 + lane];
        }
        if (rem > 8) {
          t8 = Hs[(size_t)(e8 >> 5) * 64 + lane];
          t9 = Hs[(size_t)(e9 >> 5) * 64 + lane];
          t10 = Hs[(size_t)(e10 >> 5) * 64 + lane];
          t11 = Hs[(size_t)(e11 >> 5) * 64 + lane];
        }
        if (rem > 12) {
          t12 = Hs[(size_t)(e12 >> 5) * 64 + lane];
          t13 = Hs[(size_t)(e13 >> 5) * 64 + lane];
          t14 = Hs[(size_t)(e14 >> 5) * 64 + lane];
          t15 = Hs[(size_t)(e15 >> 5) * 64 + lane];
        }
        a[(e0 & 31) * 64 + lane] += t0;
        if (1 < rem) a[(e1 & 31) * 64 + lane] += t1;
        if (2 < rem) a[(e2 & 31) * 64 + lane] += t2;
        if (3 < rem) a[(e3 & 31) * 64 + lane] += t3;
        if (4 < rem) a[(e4 & 31) * 64 + lane] += t4;
        if (5 < rem) a[(e5 & 31) * 64 + lane] += t5;
        if (6 < rem) a[(e6 & 31) * 64 + lane] += t6;
        if (7 < rem) a[(e7 & 31) * 64 + lane] += t7;
        if (8 < rem) a[(e8 & 31) * 64 + lane] += t8;
        if (9 < rem) a[(e9 & 31) * 64 + lane] += t9;
        if (10 < rem) a[(e10 & 31) * 64 + lane] += t10;
        if (11 < rem) a[(e11 & 31) * 64 + lane] += t11;
        if (12 < rem) a[(e12 & 31) * 64 + lane] += t12;
        if (13 < rem) a[(e13 & 31) * 64 + lane] += t13;
        if (14 < rem) a[(e14 & 31) * 64 + lane] += t14;
        if (15 < rem) a[(e15 & 31) * 64 + lane] += t15;
        pk = pk_next;
      }
    }
  }
  __syncthreads();
  if (!valid) return;
  // Merge the two halves; each wave writes 16 nodes.
  const float* a0 = accs[pair * 2];
  const float* a1 = accs[pair * 2 + 1];
  int dbase = half << 4;
  for (int d = dbase; d < dbase + 16; ++d) {
    int node = nodeBase + d;
    if (node >= n) break;
    float dn = dinv[node];
    float v = a0[d * 64 + lane] + a1[d * 64 + lane] +
              Hs[(size_t)node * 64 + lane];
    v = v * dn + bias[lane];
    if (POOL) {
      int g = batch[node];
      atomicAdd(&gsum[(size_t)g * 64 + lane], v);
    } else {
      outv[(size_t)node * 64 + lane] = fmaxf(v, 0.f);
    }
  }
}

// Head: per-graph wave. Node count per graph via binary search on sorted
// batch (no atomics). m = gsum/max(cnt,1); t = relu(m@W3+b3); out = t.W4+b4.
__global__ __launch_bounds__(256) void k_head(
    const float* __restrict__ gsum, const int* __restrict__ batch,
    const float* __restrict__ W3, const float* __restrict__ b3,
    const float* __restrict__ W4, const float* __restrict__ b4,
    float* __restrict__ out, int ng, int n) {
  int wid = (blockIdx.x * 256 + threadIdx.x) >> 6;
  int lane = threadIdx.x & 63;
  if (wid >= ng) return;
  int lo = 0, hi = n;
  while (lo < hi) {
    int mid = (lo + hi) >> 1;
    if (batch[mid] < wid) lo = mid + 1; else hi = mid;
  }
  int lb = lo;
  hi = n;
  while (lo < hi) {
    int mid = (lo + hi) >> 1;
    if (batch[mid] <= wid) lo = mid + 1; else hi = mid;
  }
  float cden = fmaxf((float)(lo - lb), 1.0f);
  float m = gsum[(size_t)wid * 64 + lane] / cden;
  float acc = b3[lane];
  for (int k = 0; k < 64; ++k) {
    float mk = __shfl(m, k);
    acc += mk * W3[k * 64 + lane];
  }
  acc = fmaxf(acc, 0.f);
  float r = acc * W4[lane];
  for (int off = 32; off; off >>= 1) r += __shfl_down(r, off);
  if (lane == 0) out[wid] = r + b4[0];
}

extern "C" void kernel_launch(void* const* d_in, const int* in_sizes, int n_in,
                              void* d_out, int out_size, void* d_ws, size_t ws_size,
                              hipStream_t stream) {
  const float* x = (const float*)d_in[0];
  const int* edge = (const int*)d_in[1];   // [2, E] int32
  const int* batch = (const int*)d_in[2];  // [N] int32, sorted
  const float* W1 = (const float*)d_in[3];
  const float* b1 = (const float*)d_in[4];
  const float* W2 = (const float*)d_in[5];
  const float* b2 = (const float*)d_in[6];
  const float* W3 = (const float*)d_in[7];
  const float* b3 = (const float*)d_in[8];
  const float* W4 = (const float*)d_in[9];
  const float* b4 = (const float*)d_in[10];
  float* out = (float*)d_out;

  const int n = in_sizes[0] / 64;   // 100000
  const int e = in_sizes[1] / 2;    // 1600000
  const int ng = out_size;          // 512
  const int* src = edge;
  const int* dst = edge + e;

  // Workspace layout (~59.4 MB total).
  char* ws = (char*)d_ws;
  size_t off = 0;
  auto alloc = [&](size_t bytes) -> void* {
    void* p = ws + off;
    off = (off + bytes + 255) & ~(size_t)255;
    return p;
  };
  float* A = (float*)alloc((size_t)n * 64 * 4);      // Hs (scaled gemm output)
  float* B = (float*)alloc((size_t)n * 64 * 4);      // relu out; tmp during build
  float* dinv = (float*)alloc((size_t)n * 4);
  int* cnt = (int*)alloc((size_t)n * 4);
  int* startArr = (int*)alloc((size_t)n * 4);
  int* blockCursor = (int*)alloc(3200 * 4);
  int* bucketCursor = (int*)alloc(64 * 4);
  int* bsum = (int*)alloc(1024);
  int* csr = (int*)alloc((size_t)e * 4);
  float* gsum = (float*)alloc((size_t)ng * 64 * 4);
  int* tmp = (int*)B;  // build-time only; B not live yet

  const int nb = (n + 1023) / 1024;       // scan chunks (98)
  const int ntasks = (n + 31) / 32;       // node blocks (3125)
  const int nagg = (ntasks + 1) / 2;      // agg workgroups, 2 tasks each (1563)
  const int nbuck = (ntasks + 63) / 64;   // coarse buckets (49)

  int zmax = n;
  if (ng * 64 > zmax) zmax = ng * 64;
  k_zero<<<(zmax + 255) / 256, 256, 0, stream>>>(cnt, gsum, n, ng * 64);
  k_count<<<(e + 255) / 256, 256, 0, stream>>>(dst, cnt, e);
  k_scanA<<<nb, 256, 0, stream>>>(cnt, startArr, bsum, n);
  k_scanB<<<1, 256, 0, stream>>>(bsum, nb);
  k_scanC<<<(n + 255) / 256, 256, 0, stream>>>(startArr, bsum, cnt, dinv,
                                               blockCursor, bucketCursor, n);
  k_p1<<<(e + 2047) / 2048, 256, 0, stream>>>(src, dst, bucketCursor, tmp, e);
  k_p2<<<nbuck * 8, 256, 0, stream>>>(startArr, tmp, blockCursor, csr, n, e);
  k_bsort<<<ntasks, 256, 0, stream>>>(startArr, csr, n, e);

  // Layer 1: A = (x@W1)*dinv ; B = relu(agg(A)*dinv + b1)
  k_gemm64s<<<(n + 63) / 64, 256, 0, stream>>>(x, W1, dinv, A, n);
  k_agg3<0><<<nagg, 256, 0, stream>>>(A, csr, startArr, dinv, b1, batch, B, gsum,
                                      n, e);
  // Layer 2: A = (B@W2)*dinv ; pool(agg(A)*dinv + b2)
  k_gemm64s<<<(n + 63) / 64, 256, 0, stream>>>(B, W2, dinv, A, n);
  k_agg3<1><<<nagg, 256, 0, stream>>>(A, csr, startArr, dinv, b2, batch, B, gsum,
                                      n, e);
  // Head
  k_head<<<((size_t)ng * 64 + 255) / 256, 256, 0, stream>>>(gsum, batch, W3, b3,
                                                            W4, b4, out, ng, n);
}

// Round 9
// 377.580 us; speedup vs baseline: 1.1177x; 1.1177x over previous
//
#include <hip/hip_runtime.h>
#include <math.h>

// ---------------------------------------------------------------------------
// GCN: h1 = relu(norm_agg(x@W1)+b1); h2 = norm_agg(h1@W2)+b2;
//      g = mean_pool(h2, batch); out = relu(g@W3+b3)@W4 + b4
// norm_agg(h)[d] = (sum_{e: dst=d} h[src]*dinv[src] + h[d]*dinv[d]) * dinv[d]
// Build (block-granular only -- no per-node scan): LDS histogram over 3125
// dst-blocks -> 1-block scan -> two-level line-dense scatter (49 buckets,
// then 64 blocks/bucket) -> per-block src sort (+deg count -> dinv).
// Aggregation: wave owns 32 dsts (8 KB LDS acc), sweeps its src-sorted
// segment (collective L2-resident front), 16 gathers in flight + index
// prefetch. GEMM epilogue pre-scales rows by dinv. Graph node-counts via
// binary search on sorted batch (no atomics).
// ---------------------------------------------------------------------------

#define NBLK 3125  // (100000+31)/32; guarded generically below

__global__ __launch_bounds__(256) void k_init(float* gsum, int* blockCnt,
                                              int gsz, int nblk) {
  int i = blockIdx.x * 256 + threadIdx.x;
  if (i < gsz) gsum[i] = 0.f;
  if (i < nblk + 64) blockCnt[i] = 0;
}

// Histogram of dst>>5 into nblk bins via LDS (12.8 KB), merged to global.
__global__ __launch_bounds__(256) void k_histB(const int* __restrict__ dst,
                                               int* __restrict__ blockCnt,
                                               int e, int nblk) {
  __shared__ int h[3200];
  int t = threadIdx.x;
  for (int i = t; i < 3200; i += 256) h[i] = 0;
  __syncthreads();
  int base = blockIdx.x * 8192;
#pragma unroll
  for (int k = 0; k < 32; ++k) {
    int i = base + k * 256 + t;
    if (i < e) atomicAdd(&h[dst[i] >> 5], 1);
  }
  __syncthreads();
  for (int i = t; i < nblk; i += 256) {
    int v = h[i];
    if (v) atomicAdd(&blockCnt[i], v);
  }
}

// Single-block exclusive scan of blockCnt[nblk]; writes blockBase (nblk+1,
// last = total), blockCursor (=base), bucketCursor (every 64th block).
__global__ __launch_bounds__(256) void k_scan(const int* __restrict__ blockCnt,
                                              int* __restrict__ blockBase,
                                              int* __restrict__ blockCursor,
                                              int* __restrict__ bucketCursor,
                                              int nblk, int nbuck) {
  __shared__ int sh[256];
  __shared__ int carry;
  int t = threadIdx.x;
  if (t == 0) carry = 0;
  __syncthreads();
  int nchunk = (nblk + 255) / 256;
  for (int ch = 0; ch < nchunk; ++ch) {
    int idx = ch * 256 + t;
    int v = (idx < nblk) ? blockCnt[idx] : 0;
    sh[t] = v;
    __syncthreads();
    for (int off = 1; off < 256; off <<= 1) {
      int x = (t >= off) ? sh[t - off] : 0;
      __syncthreads();
      sh[t] += x;
      __syncthreads();
    }
    int base = carry;
    int b = base + sh[t] - v;
    if (idx < nblk) {
      blockBase[idx] = b;
      blockCursor[idx] = b;
      if ((idx & 63) == 0 && (idx >> 6) < nbuck) bucketCursor[idx >> 6] = b;
    }
    __syncthreads();
    if (t == 255) carry = base + sh[255];
    __syncthreads();
  }
  if (t == 0) blockBase[nblk] = carry;  // total = e
}

// Pass 1: bin edges into coarse buckets (2048 nodes each) with range-dense
// writes. Entry = (dstLow6<<22) | (src<<5) | dstLocal.
__global__ __launch_bounds__(256) void k_p1(const int* __restrict__ src,
                                            const int* __restrict__ dst,
                                            int* __restrict__ bucketCursor,
                                            int* __restrict__ tmp, int e) {
  __shared__ int hist[64];
  __shared__ int gbase[64];
  int t = threadIdx.x;
  int base = blockIdx.x * 2048;
  if (t < 64) hist[t] = 0;
  __syncthreads();
  int ent[8], rk[8], bk[8];
#pragma unroll
  for (int k = 0; k < 8; ++k) {
    int i = base + k * 256 + t;
    bool v = i < e;
    int s = v ? src[i] : 0;
    int d = v ? dst[i] : 0;
    bk[k] = d >> 11;
    ent[k] = (((d >> 5) & 63) << 22) | (s << 5) | (d & 31);
    rk[k] = v ? atomicAdd(&hist[bk[k]], 1) : -1;
  }
  __syncthreads();
  if (t < 64 && hist[t] > 0) gbase[t] = atomicAdd(&bucketCursor[t], hist[t]);
  __syncthreads();
#pragma unroll
  for (int k = 0; k < 8; ++k)
    if (rk[k] >= 0) tmp[gbase[bk[k]] + rk[k]] = ent[k];
}

// Pass 2: within each bucket (8 slices/bucket), bin entries to their dst-block
// segment (64 bins), range-dense writes; strip top 6 bits for final csr.
__global__ __launch_bounds__(256) void k_p2(const int* __restrict__ blockBase,
                                            const int* __restrict__ tmp,
                                            int* __restrict__ blockCursor,
                                            int* __restrict__ csr, int nblk) {
  __shared__ int hist[64];
  __shared__ int gbase[64];
  int b = blockIdx.x >> 3;
  int sl = blockIdx.x & 7;
  int hiIdx = (b + 1) << 6;
  if (hiIdx > nblk) hiIdx = nblk;
  int lo_b = blockBase[b << 6];
  int hi_b = blockBase[hiIdx];
  int len = hi_b - lo_b;
  int lo = lo_b + (int)(((long long)len * sl) >> 3);
  int hi = lo_b + (int)(((long long)len * (sl + 1)) >> 3);
  int t = threadIdx.x;
  for (int rbase = lo; rbase < hi; rbase += 2048) {
    if (t < 64) hist[t] = 0;
    __syncthreads();
    int ent[8], rk[8], bin[8];
#pragma unroll
    for (int k = 0; k < 8; ++k) {
      int i = rbase + k * 256 + t;
      bool v = i < hi;
      int en = v ? tmp[i] : 0;
      ent[k] = en;
      bin[k] = en >> 22;
      rk[k] = v ? atomicAdd(&hist[bin[k]], 1) : -1;
    }
    __syncthreads();
    if (t < 64 && hist[t] > 0)
      gbase[t] = atomicAdd(&blockCursor[(b << 6) + t], hist[t]);
    __syncthreads();
#pragma unroll
    for (int k = 0; k < 8; ++k)
      if (rk[k] >= 0) csr[gbase[bin[k]] + rk[k]] = ent[k] & 0x3FFFFF;
    __syncthreads();
  }
}

// Per-node-block (32 dsts): count degrees -> dinv, then counting-sort the
// packed segment by src>>11 (locality-only; skipped for oversize segments).
__global__ __launch_bounds__(256) void k_bsort(const int* __restrict__ blockBase,
                                               int* __restrict__ csr,
                                               float* __restrict__ dinv, int n) {
  __shared__ int in_sh[1024];
  __shared__ int out_sh[1024];
  __shared__ int hist[64];
  __shared__ int hscan[64];
  __shared__ int deg[32];
  int blk = blockIdx.x;
  int nodeBase = blk << 5;
  if (nodeBase >= n) return;
  int p0 = blockBase[blk];
  int p1 = blockBase[blk + 1];
  int seg = p1 - p0;
  int t = threadIdx.x;
  if (t < 32) deg[t] = 0;
  __syncthreads();
  for (int i = t; i < seg; i += 256) atomicAdd(&deg[csr[p0 + i] & 31], 1);
  __syncthreads();
  if (t < 32 && nodeBase + t < n)
    dinv[nodeBase + t] = 1.0f / sqrtf((float)(deg[t] + 1));
  if (seg <= 0 || seg > 1024) return;  // block-uniform
  if (t < 64) hist[t] = 0;
  __syncthreads();
  for (int i = t; i < seg; i += 256) {
    int v = csr[p0 + i];
    in_sh[i] = v;
    atomicAdd(&hist[v >> 16], 1);  // (src<<5)>>16 == src>>11
  }
  __syncthreads();
  if (t == 0) {
    int s = 0;
    for (int b = 0; b < 64; ++b) {
      hscan[b] = s;
      s += hist[b];
    }
  }
  __syncthreads();
  for (int i = t; i < seg; i += 256) {
    int v = in_sh[i];
    int pos = atomicAdd(&hscan[v >> 16], 1);
    out_sh[pos] = v;
  }
  __syncthreads();
  for (int i = t; i < seg; i += 256) csr[p0 + i] = out_sh[i];
}

// Y[N,64] = (X[N,64] @ W[64,64]) * dinv[row]  (row-scaled epilogue).
__global__ __launch_bounds__(256) void k_gemm64s(const float* __restrict__ X,
                                                 const float* __restrict__ W,
                                                 const float* __restrict__ dinv,
                                                 float* __restrict__ Y, int n) {
  __shared__ float Xs[64 * 65];
  __shared__ float Ws[64 * 64];
  int t = threadIdx.x;
  int r0 = blockIdx.x << 6;
  for (int i = t * 4; i < 4096; i += 1024)
    *(float4*)&Ws[i] = *(const float4*)&W[i];
  for (int s = t; s < 1024; s += 256) {
    int r = s >> 4, c4 = (s & 15) << 2;
    float4 v = make_float4(0.f, 0.f, 0.f, 0.f);
    if (r0 + r < n) v = *(const float4*)&X[(size_t)(r0 + r) * 64 + c4];
    Xs[r * 65 + c4 + 0] = v.x;
    Xs[r * 65 + c4 + 1] = v.y;
    Xs[r * 65 + c4 + 2] = v.z;
    Xs[r * 65 + c4 + 3] = v.w;
  }
  __syncthreads();
  int c4 = (t & 15) << 2;
  int rb = (t >> 4) << 2;
  float4 a0 = {0, 0, 0, 0}, a1 = {0, 0, 0, 0}, a2 = {0, 0, 0, 0}, a3 = {0, 0, 0, 0};
  for (int k = 0; k < 64; ++k) {
    float4 w = *(const float4*)&Ws[k * 64 + c4];
    float x0 = Xs[(rb + 0) * 65 + k];
    float x1 = Xs[(rb + 1) * 65 + k];
    float x2 = Xs[(rb + 2) * 65 + k];
    float x3 = Xs[(rb + 3) * 65 + k];
    a0.x += x0 * w.x; a0.y += x0 * w.y; a0.z += x0 * w.z; a0.w += x0 * w.w;
    a1.x += x1 * w.x; a1.y += x1 * w.y; a1.z += x1 * w.z; a1.w += x1 * w.w;
    a2.x += x2 * w.x; a2.y += x2 * w.y; a2.z += x2 * w.z; a2.w += x2 * w.w;
    a3.x += x3 * w.x; a3.y += x3 * w.y; a3.z += x3 * w.z; a3.w += x3 * w.w;
  }
  int r = r0 + rb;
  if (r + 0 < n) {
    float s0 = dinv[r + 0];
    a0.x *= s0; a0.y *= s0; a0.z *= s0; a0.w *= s0;
    *(float4*)&Y[(size_t)(r + 0) * 64 + c4] = a0;
  }
  if (r + 1 < n) {
    float s1 = dinv[r + 1];
    a1.x *= s1; a1.y *= s1; a1.z *= s1; a1.w *= s1;
    *(float4*)&Y[(size_t)(r + 1) * 64 + c4] = a1;
  }
  if (r + 2 < n) {
    float s2 = dinv[r + 2];
    a2.x *= s2; a2.y *= s2; a2.z *= s2; a2.w *= s2;
    *(float4*)&Y[(size_t)(r + 2) * 64 + c4] = a2;
  }
  if (r + 3 < n) {
    float s3 = dinv[r + 3];
    a3.x *= s3; a3.y *= s3; a3.z *= s3; a3.w *= s3;
    *(float4*)&Y[(size_t)(r + 3) * 64 + c4] = a3;
  }
}

// Aggregation: one wave per task of 32 dsts (full segment, lowest traffic --
// R7 config), rounds of 16 with index prefetch. POOL=0: relu store; POOL=1:
// coalesced atomicAdd into gsum.
template <int POOL>
__global__ __launch_bounds__(256) void k_agg(
    const float* __restrict__ Hs, const int* __restrict__ csr,
    const int* __restrict__ blockBase, const float* __restrict__ dinv,
    const float* __restrict__ bias, const int* __restrict__ batch,
    float* __restrict__ outv, float* __restrict__ gsum, int n) {
  __shared__ float accs[4][32 * 64];  // 32 KB / block
  int t = threadIdx.x;
  int w = t >> 6, lane = t & 63;
  int task = blockIdx.x * 4 + w;
  int nodeBase = task << 5;
  if (nodeBase >= n) return;  // wave-uniform; no block syncs below
  float* a = accs[w];
#pragma unroll 4
  for (int d = 0; d < 32; ++d) a[d * 64 + lane] = 0.f;
  int p0 = blockBase[task];
  int p1 = blockBase[task + 1];
  int c = p1 - p0;
  if (c > 0) {
    int sub = lane & 15;
    int qlast = p1 - 1;
    int qq = p0 + sub;
    int pk = csr[qq < qlast ? qq : qlast];  // round-0 indices
    for (int rb = 0; rb < c; rb += 16) {
      int pk_next = 0;
      bool more = (rb + 16) < c;  // wave-uniform
      if (more) {
        int qn = p0 + rb + 16 + sub;
        pk_next = csr[qn < qlast ? qn : qlast];  // prefetch next round
      }
      int rem = c - rb;  // wave-uniform
      int e0 = __builtin_amdgcn_readlane(pk, 0);
      int e1 = __builtin_amdgcn_readlane(pk, 1);
      int e2 = __builtin_amdgcn_readlane(pk, 2);
      int e3 = __builtin_amdgcn_readlane(pk, 3);
      int e4 = __builtin_amdgcn_readlane(pk, 4);
      int e5 = __builtin_amdgcn_readlane(pk, 5);
      int e6 = __builtin_amdgcn_readlane(pk, 6);
      int e7 = __builtin_amdgcn_readlane(pk, 7);
      int e8 = __builtin_amdgcn_readlane(pk, 8);
      int e9 = __builtin_amdgcn_readlane(pk, 9);
      int e10 = __builtin_amdgcn_readlane(pk, 10);
      int e11 = __builtin_amdgcn_readlane(pk, 11);
      int e12 = __builtin_amdgcn_readlane(pk, 12);
      int e13 = __builtin_amdgcn_readlane(pk, 13);
      int e14 = __builtin_amdgcn_readlane(pk, 14);
      int e15 = __builtin_amdgcn_readlane(pk, 15);
      float t0 = 0.f, t1 = 0.f, t2 = 0.f, t3 = 0.f;
      float t4 = 0.f, t5 = 0.f, t6 = 0.f, t7 = 0.f;
      float t8 = 0.f, t9 = 0.f, t10 = 0.f, t11 = 0.f;
      float t12 = 0.f, t13 = 0.f, t14 = 0.f, t15 = 0.f;
      {
        t0 = Hs[(size_t)(e0 >> 5) * 64 + lane];
        t1 = Hs[(size_t)(e1 >> 5) * 64 + lane];
        t2 = Hs[(size_t)(e2 >> 5) * 64 + lane];
        t3 = Hs[(size_t)(e3 >> 5) * 64 + lane];
      }
      if (rem > 4) {
        t4 = Hs[(size_t)(e4 >> 5) * 64 + lane];
        t5 = Hs[(size_t)(e5 >> 5) * 64 + lane];
        t6 = Hs[(size_t)(e6 >> 5) * 64 + lane];
        t7 = Hs[(size_t)(e7 >> 5) * 64 + lane];
      }
      if (rem > 8) {
        t8 = Hs[(size_t)(e8 >> 5) * 64 + lane];
        t9 = Hs[(size_t)(e9 >> 5) * 64 + lane];
        t10 = Hs[(size_t)(e10 >> 5) * 64 + lane];
        t11 = Hs[(size_t)(e11 >> 5) * 64 + lane];
      }
      if (rem > 12) {
        t12 = Hs[(size_t)(e12 >> 5) * 64 + lane];
        t13 = Hs[(size_t)(e13 >> 5) * 64 + lane];
        t14 = Hs[(size_t)(e14 >> 5) * 64 + lane];
        t15 = Hs[(size_t)(e15 >> 5) * 64 + lane];
      }
      a[(e0 & 31) * 64 + lane] += t0;
      if (1 < rem) a[(e1 & 31) * 64 + lane] += t1;
      if (2 < rem) a[(e2 & 31) * 64 + lane] += t2;
      if (3 < rem) a[(e3 & 31) * 64 + lane] += t3;
      if (4 < rem) a[(e4 & 31) * 64 + lane] += t4;
      if (5 < rem) a[(e5 & 31) * 64 + lane] += t5;
      if (6 < rem) a[(e6 & 31) * 64 + lane] += t6;
      if (7 < rem) a[(e7 & 31) * 64 + lane] += t7;
      if (8 < rem) a[(e8 & 31) * 64 + lane] += t8;
      if (9 < rem) a[(e9 & 31) * 64 + lane] += t9;
      if (10 < rem) a[(e10 & 31) * 64 + lane] += t10;
      if (11 < rem) a[(e11 & 31) * 64 + lane] += t11;
      if (12 < rem) a[(e12 & 31) * 64 + lane] += t12;
      if (13 < rem) a[(e13 & 31) * 64 + lane] += t13;
      if (14 < rem) a[(e14 & 31) * 64 + lane] += t14;
      if (15 < rem) a[(e15 & 31) * 64 + lane] += t15;
      pk = pk_next;
    }
  }
  for (int d = 0; d < 32; ++d) {
    int node = nodeBase + d;
    if (node >= n) break;
    float dn = dinv[node];
    float v = a[d * 64 + lane] + Hs[(size_t)node * 64 + lane];
    v = v * dn + bias[lane];
    if (POOL) {
      int g = batch[node];
      atomicAdd(&gsum[(size_t)g * 64 + lane], v);
    } else {
      outv[(size_t)node * 64 + lane] = fmaxf(v, 0.f);
    }
  }
}

// Head: per-graph wave. Node count via binary search on sorted batch.
__global__ __launch_bounds__(256) void k_head(
    const float* __restrict__ gsum, const int* __restrict__ batch,
    const float* __restrict__ W3, const float* __restrict__ b3,
    const float* __restrict__ W4, const float* __restrict__ b4,
    float* __restrict__ out, int ng, int n) {
  int wid = (blockIdx.x * 256 + threadIdx.x) >> 6;
  int lane = threadIdx.x & 63;
  if (wid >= ng) return;
  int lo = 0, hi = n;
  while (lo < hi) {
    int mid = (lo + hi) >> 1;
    if (batch[mid] < wid) lo = mid + 1; else hi = mid;
  }
  int lb = lo;
  hi = n;
  while (lo < hi) {
    int mid = (lo + hi) >> 1;
    if (batch[mid] <= wid) lo = mid + 1; else hi = mid;
  }
  float cden = fmaxf((float)(lo - lb), 1.0f);
  float m = gsum[(size_t)wid * 64 + lane] / cden;
  float acc = b3[lane];
  for (int k = 0; k < 64; ++k) {
    float mk = __shfl(m, k);
    acc += mk * W3[k * 64 + lane];
  }
  acc = fmaxf(acc, 0.f);
  float r = acc * W4[lane];
  for (int off = 32; off; off >>= 1) r += __shfl_down(r, off);
  if (lane == 0) out[wid] = r + b4[0];
}

extern "C" void kernel_launch(void* const* d_in, const int* in_sizes, int n_in,
                              void* d_out, int out_size, void* d_ws, size_t ws_size,
                              hipStream_t stream) {
  const float* x = (const float*)d_in[0];
  const int* edge = (const int*)d_in[1];   // [2, E] int32
  const int* batch = (const int*)d_in[2];  // [N] int32, sorted
  const float* W1 = (const float*)d_in[3];
  const float* b1 = (const float*)d_in[4];
  const float* W2 = (const float*)d_in[5];
  const float* b2 = (const float*)d_in[6];
  const float* W3 = (const float*)d_in[7];
  const float* b3 = (const float*)d_in[8];
  const float* W4 = (const float*)d_in[9];
  const float* b4 = (const float*)d_in[10];
  float* out = (float*)d_out;

  const int n = in_sizes[0] / 64;   // 100000
  const int e = in_sizes[1] / 2;    // 1600000
  const int ng = out_size;          // 512
  const int* src = edge;
  const int* dst = edge + e;

  // Workspace layout.
  char* ws = (char*)d_ws;
  size_t off = 0;
  auto alloc = [&](size_t bytes) -> void* {
    void* p = ws + off;
    off = (off + bytes + 255) & ~(size_t)255;
    return p;
  };
  float* A = (float*)alloc((size_t)n * 64 * 4);   // Hs (scaled gemm output)
  float* B = (float*)alloc((size_t)n * 64 * 4);   // relu out; tmp during build
  float* dinv = (float*)alloc((size_t)n * 4);
  int* blockCnt = (int*)alloc(3264 * 4);
  int* blockBase = (int*)alloc(3264 * 4);
  int* blockCursor = (int*)alloc(3264 * 4);
  int* bucketCursor = (int*)alloc(64 * 4);
  int* csr = (int*)alloc((size_t)e * 4);
  float* gsum = (float*)alloc((size_t)ng * 64 * 4);
  int* tmp = (int*)B;  // build-time only; B not live yet

  const int nblk = (n + 31) / 32;        // 3125 dst-blocks
  const int nbuck = (nblk + 63) / 64;    // 49 coarse buckets
  const int nagg = (nblk + 3) / 4;       // agg workgroups (782)
  const int gsz = ng * 64;

  int zmax = gsz > nblk + 64 ? gsz : nblk + 64;
  k_init<<<(zmax + 255) / 256, 256, 0, stream>>>(gsum, blockCnt, gsz, nblk);
  k_histB<<<(e + 8191) / 8192, 256, 0, stream>>>(dst, blockCnt, e, nblk);
  k_scan<<<1, 256, 0, stream>>>(blockCnt, blockBase, blockCursor, bucketCursor,
                                nblk, nbuck);
  k_p1<<<(e + 2047) / 2048, 256, 0, stream>>>(src, dst, bucketCursor, tmp, e);
  k_p2<<<nbuck * 8, 256, 0, stream>>>(blockBase, tmp, blockCursor, csr, nblk);
  k_bsort<<<nblk, 256, 0, stream>>>(blockBase, csr, dinv, n);

  // Layer 1: A = (x@W1)*dinv ; B = relu(agg(A)*dinv + b1)
  k_gemm64s<<<(n + 63) / 64, 256, 0, stream>>>(x, W1, dinv, A, n);
  k_agg<0><<<nagg, 256, 0, stream>>>(A, csr, blockBase, dinv, b1, batch, B, gsum, n);
  // Layer 2: A = (B@W2)*dinv ; pool(agg(A)*dinv + b2)
  k_gemm64s<<<(n + 63) / 64, 256, 0, stream>>>(B, W2, dinv, A, n);
  k_agg<1><<<nagg, 256, 0, stream>>>(A, csr, blockBase, dinv, b2, batch, B, gsum, n);
  // Head
  k_head<<<((size_t)ng * 64 + 255) / 256, 256, 0, stream>>>(gsum, batch, W3, b3,
                                                            W4, b4, out, ng, n);
}